// Round 10
// baseline (2220.534 us; speedup 1.0000x reference)
//
#include <hip/hip_runtime.h>

// Fused 4-layer MLP (2 -> 1024 -> 512 -> 256 -> 3), N = 262144, fp32 I/O.
// R10: R8 base (512 thr / 8 waves, 64 rows/block, 4096 blocks, 2jt x 2mt,
// 64 KB static LDS) + zero-register ping-pong:
//  - two 32 KB h1 buffers (chunk = 256 feats), XOR-swizzled (free 2-way
//    banking, NO padding -> exactly 64 KB), addressed through 12 precomputed
//    base pointers + full unroll -> pure immediate ds offsets.
//  - STAGE(c+1) overlaps KCHUNK(c); main barriers 8 -> 4.
//  - bias init moved out of main scope: acc start at zero, b1/b2 added in
//    the tail from C-layout fp32 tables (B1C/B2C) -> no ones/zero16/B1F regs.
//  - HARD INVARIANT (R9 post-mortem): arch VGPR <= 64. 64 arch + 64 AGPR
//    = 128/thread = 4 waves/SIMD; at 68 arch the 8-wave block drops to
//    1 block/CU (occupancy 23%, R9). __launch_bounds__(512,4) pins it.

typedef _Float16 f16;
typedef f16 f16x8 __attribute__((ext_vector_type(8)));
typedef f16 f16x4 __attribute__((ext_vector_type(4)));
typedef float f32x16 __attribute__((ext_vector_type(16)));

#define MFMA(a, b, c) __builtin_amdgcn_mfma_f32_32x32x16_f16((a), (b), (c), 0, 0, 0)

// ws layout in 16-byte units (f16x8):
//  W1F : [16 jt][64 ks][64 lane]            ->      0 .. 65536
//  W2F : [ 8 jt][32 ks][64 lane]            ->  65536 .. 81920
//  W3F : [16 ks][64 lane]                   ->  81920 .. 82944
//  P0F : [32 k1t][64 lane] (layer1 A frag)  ->  82944 .. 84992
//  B1F : [16 jt][64 lane] (unused by R10)   ->  84992 .. 86016
//  B2F : [ 8 jt][64 lane] (unused by R10)   ->  86016 .. 86528
//  B1C : b1 in C-layout fp32 [16jt][64 lane][16 r] -> 86528 .. 90624
//  B2C : b2 in C-layout fp32 [ 8jt][64 lane][16 r] -> 90624 .. 92672
#define U_W1F 0
#define U_W2F 65536
#define U_W3F 81920
#define U_P0F 82944
#define U_B1F 84992
#define U_B2F 86016
#define U_B1C 86528
#define U_B2C 90624
#define U_TOT2 92672

__global__ void prep_kernel(const float* __restrict__ W0, const float* __restrict__ b0,
                            const float* __restrict__ W1, const float* __restrict__ b1,
                            const float* __restrict__ W2, const float* __restrict__ b2,
                            const float* __restrict__ W3, f16* __restrict__ ws)
{
    int u = blockIdx.x * 256 + threadIdx.x;
    if (u >= U_TOT2) return;
    int lane = u & 63;
    int l31 = lane & 31;
    int q = lane >> 5;

    if (u >= U_B1C) {   // bias tables in C-layout fp32 (float4 per slot)
        const float* bsrc;
        int t;
        if (u < U_B2C) { bsrc = b1; t = u - U_B1C; }
        else           { bsrc = b2; t = u - U_B2C; }
        int f0 = t * 4;
        int jt = f0 >> 10;
        int ln = (f0 >> 4) & 63;
        int g  = (f0 >> 2) & 3;          // r = g*4 + e
        int base = jt * 32 + 8 * g + 4 * (ln >> 5);   // + e for e=0..3
        float4 v4 = *(const float4*)(bsrc + base);
        ((float4*)ws)[u] = v4;
        return;
    }

    f16x8 v;
#pragma unroll
    for (int e = 0; e < 8; ++e) v[e] = (f16)0.f;

    if (u < U_W2F) {                       // W1F: W1 is [1024][512]
        int jt = u >> 12, ks = (u >> 6) & 63;
        int j = jt * 32 + l31;
        int kb = ks * 16 + q * 8;
        const float* p = W1 + (size_t)kb * 512 + j;
#pragma unroll
        for (int e = 0; e < 8; ++e) v[e] = (f16)p[(size_t)e * 512];
    } else if (u < U_W3F) {                // W2F: W2 is [512][256]
        int t = u - U_W2F;
        int jt = t >> 11, ks = (t >> 6) & 31;
        int j = jt * 32 + l31;
        int kb = ks * 16 + q * 8;
        const float* p = W2 + (size_t)kb * 256 + j;
#pragma unroll
        for (int e = 0; e < 8; ++e) v[e] = (f16)p[(size_t)e * 256];
    } else if (u < U_P0F) {                // W3F: W3 is [256][3], pad j>=3 with 0
        int t = u - U_W3F;
        int ks = t >> 6;
        int j = l31;
        int kb = ks * 16 + q * 8;
        if (j < 3) {
            const float* p = W3 + (size_t)kb * 3 + j;
#pragma unroll
            for (int e = 0; e < 8; ++e) v[e] = (f16)p[(size_t)e * 3];
        }
    } else if (u < U_B1F) {                // P0F: layer-1 A frag with hi/lo split + bias
        int t = u - U_P0F;
        int jt = t >> 6;
        int j = jt * 32 + l31;
        if (q == 0) {
            float w00 = W0[j], w01 = W0[1024 + j], bb = b0[j];
            f16 w00h = (f16)w00, w01h = (f16)w01, bh = (f16)bb;
            v[0] = w00h; v[1] = w01h; v[2] = bh;
            v[3] = w00h; v[4] = w01h;                       // pair with x_lo
            v[5] = (f16)(w00 - (float)w00h);                // w_lo * x_hi
            v[6] = (f16)(w01 - (float)w01h);
            v[7] = (f16)(bb - (float)bh);                   // bias residual * 1
        }
    } else if (u < U_B2F) {                // B1F (legacy, unused)
        int t = u - U_B1F;
        int jt = t >> 6;
        int j = jt * 32 + l31;
        if (q == 0) v[0] = (f16)b1[j];
    } else {                               // B2F (legacy, unused)
        int t = u - U_B2F;
        int jt = t >> 6;
        int j = jt * 32 + l31;
        if (q == 0) v[0] = (f16)b2[j];
    }
    ((f16x8*)ws)[u] = v;
}

// ---- XOR-swizzled slab helpers (tail h2/h3 only; VALU there is fine).
__device__ __forceinline__ void slab_write4(unsigned char* lds, int m, int dw /*even*/,
                                            int rs, f16x4 val)
{
    int s = (m & 15) << 1;
    *(f16x4*)(lds + (size_t)m * rs + (size_t)((dw ^ s) << 2)) = val;
}

__device__ __forceinline__ f16x8 slab_read8(const unsigned char* lds, int m, int dw /*mult of 4*/,
                                            int rs)
{
    int s = (m & 15) << 1;
    f16x4 lo = *(const f16x4*)(lds + (size_t)m * rs + (size_t)((dw ^ s) << 2));
    f16x4 hi = *(const f16x4*)(lds + (size_t)m * rs + (size_t)(((dw + 2) ^ s) << 2));
    union { f16x8 v; f16x4 p[2]; } u;
    u.p[0] = lo; u.p[1] = hi;
    return u.v;
}

__device__ __forceinline__ f16x4 relu_pack4(const f32x16& d, int t)
{
    f16x4 pk;
#pragma unroll
    for (int r = 0; r < 4; ++r) {
        float v = d[4 * t + r];
        pk[r] = (f16)(v > 0.f ? v : 0.f);
    }
    return pk;
}

__global__ __launch_bounds__(512, 4)
void mlp_kernel(const float* __restrict__ X, const float* __restrict__ b3,
                const f16* __restrict__ ws, float* __restrict__ out)
{
    const f16x8* W1F = (const f16x8*)ws + U_W1F;
    const f16x8* W2F = (const f16x8*)ws + U_W2F;
    const f16x8* W3F = (const f16x8*)ws + U_W3F;
    const f16x8* P0F = (const f16x8*)ws + U_P0F;

    __shared__ __align__(16) unsigned char lds[65536];

    const int tid  = threadIdx.x;
    const int w    = tid >> 6;       // wave 0..7
    const int lane = tid & 63;
    const int l31  = lane & 31;
    const int q    = lane >> 5;
    const size_t rowbase = (size_t)blockIdx.x * 64;

    // Layer-1 split: wave w stages m-tile (w&1), k1-slots (w>>1) and (w>>1)+4.
    const int mtL1 = w & 1;
    const int k1a  = w >> 1;

    // X frag (hi/lo split -> layer 1 ~exact)
    f16x8 xfrag;
    {
        f16x8 v;
#pragma unroll
        for (int e = 0; e < 8; ++e) v[e] = (f16)0.f;
        if (q == 0) {
            float2 xv = ((const float2*)X)[rowbase + mtL1 * 32 + l31];
            f16 x0h = (f16)xv.x, x1h = (f16)xv.y;
            v[0] = x0h; v[1] = x1h; v[2] = (f16)1.f;
            v[3] = (f16)(xv.x - (float)x0h);
            v[4] = (f16)(xv.y - (float)x1h);
            v[5] = x0h; v[6] = x1h; v[7] = (f16)1.f;
        }
        xfrag = v;
    }

    // XOR swizzle (dw units): phys_dw = dw ^ ((row&15)<<1). Precomputed bases:
    const int s_ = (l31 & 15) << 1;
    unsigned pq[8];                 // read: [j] lo, [j+4] hi; j = ks&3
#pragma unroll
    for (int j = 0; j < 4; ++j) {
        int dwlo = j * 8 + q * 4;
        pq[j]     = l31 * 512 + (unsigned)(((dwlo)     ^ s_) << 2);
        pq[j + 4] = l31 * 512 + (unsigned)(((dwlo + 2) ^ s_) << 2);
    }
    unsigned pwa[4];                // write: [t]
    {
        int m1 = mtL1 * 32 + l31;
#pragma unroll
        for (int t = 0; t < 4; ++t)
            pwa[t] = m1 * 512 + (unsigned)(((k1a * 16 + q * 2 + t * 4) ^ s_) << 2);
    }

    // Layer-2 accumulators: wave w -> j-tiles 2w, 2w+1; both m-tiles. Zero-init;
    // bias b1 is added in the tail (keeps ones/zero16/B1F out of the reg budget).
    const int jt0 = w * 2;
    f32x16 acc2[2][2] = {};

#define STAGE(cc, BOFF) do {                                                  \
    f16x8 afp0 = P0F[((cc) * 8 + k1a) * 64 + lane];                           \
    f16x8 afp1 = P0F[((cc) * 8 + k1a + 4) * 64 + lane];                       \
    f32x16 d0 = {}; d0 = MFMA(afp0, xfrag, d0);                               \
    f32x16 d1 = {}; d1 = MFMA(afp1, xfrag, d1);                               \
    _Pragma("unroll")                                                         \
    for (int t = 0; t < 4; ++t) {                                             \
        *(f16x4*)(lds + pwa[t] + (BOFF))       = relu_pack4(d0, t);           \
        *(f16x4*)(lds + pwa[t] + (BOFF) + 256) = relu_pack4(d1, t);           \
    }                                                                         \
} while (0)

#define KCHUNK(c, BOFF) do {                                                  \
    const f16x8* pa = W1F + ((size_t)jt0 * 64 + (c) * 16) * 64 + lane;        \
    _Pragma("unroll")                                                         \
    for (int ks = 0; ks < 16; ++ks) {                                         \
        f16x8 af0 = pa[ks * 64];                                              \
        f16x8 af1 = pa[(64 + ks) * 64];                                       \
        union { f16x8 v; f16x4 p[2]; } u0, u1;                                \
        u0.p[0] = *(const f16x4*)(lds + pq[ks & 3]       + (ks >> 2) * 128 + (BOFF));          \
        u0.p[1] = *(const f16x4*)(lds + pq[(ks & 3) + 4] + (ks >> 2) * 128 + (BOFF));          \
        u1.p[0] = *(const f16x4*)(lds + pq[ks & 3]       + (ks >> 2) * 128 + (BOFF) + 16384);  \
        u1.p[1] = *(const f16x4*)(lds + pq[(ks & 3) + 4] + (ks >> 2) * 128 + (BOFF) + 16384);  \
        acc2[0][0] = MFMA(af0, u0.v, acc2[0][0]);                             \
        acc2[0][1] = MFMA(af0, u1.v, acc2[0][1]);                             \
        acc2[1][0] = MFMA(af1, u0.v, acc2[1][0]);                             \
        acc2[1][1] = MFMA(af1, u1.v, acc2[1][1]);                             \
    }                                                                         \
} while (0)

    // ---- fused layer1 + layer2: 4 chunks x 256 feats, ping-pong 2x32KB
    STAGE(0, 0);
    __syncthreads();
    STAGE(1, 32768);
    KCHUNK(0, 0);
    __syncthreads();
    STAGE(2, 0);
    KCHUNK(1, 32768);
    __syncthreads();
    STAGE(3, 32768);
    KCHUNK(2, 0);
    __syncthreads();
    KCHUNK(3, 32768);
    __syncthreads();

#undef STAGE
#undef KCHUNK

    // ---- stage h2 (64 rows x 512 feats = 64KB, rs=1024B, XOR), + bias b1
    {
        const float4* B1C = (const float4*)((const char*)ws + (size_t)U_B1C * 16);
#pragma unroll
        for (int ji = 0; ji < 2; ++ji) {
            const float4* pb1 = B1C + ((size_t)(jt0 + ji) * 64 + lane) * 4;
            float4 bv[4];
#pragma unroll
            for (int g = 0; g < 4; ++g) bv[g] = pb1[g];
            int jb = (jt0 + ji) * 32 + 4 * q;
#pragma unroll
            for (int mt = 0; mt < 2; ++mt) {
                int m = mt * 32 + l31;
#pragma unroll
                for (int t = 0; t < 4; ++t) {
                    const float* bt = (const float*)&bv[t];
                    f16x4 pk;
#pragma unroll
                    for (int r = 0; r < 4; ++r) {
                        float v = acc2[ji][mt][4 * t + r] + bt[r];
                        pk[r] = (f16)(v > 0.f ? v : 0.f);
                    }
                    slab_write4(lds, m, (jb + 8 * t) >> 1, 1024, pk);
                }
            }
        }
    }
    __syncthreads();

    // ---- layer 3 full-K (512): wave w -> j-tile w, both m-tiles (bias in h3 pack)
    f32x16 acc3[2] = {};
#pragma unroll 4
    for (int ks = 0; ks < 32; ++ks) {
        f16x8 af = W2F[(w * 32 + ks) * 64 + lane];
        int dw = (ks * 16 + q * 8) >> 1;
        f16x8 bf0 = slab_read8(lds, l31, dw, 1024);
        f16x8 bf1 = slab_read8(lds, 32 + l31, dw, 1024);
        acc3[0] = MFMA(af, bf0, acc3[0]);
        acc3[1] = MFMA(af, bf1, acc3[1]);
    }
    __syncthreads();   // h2 reads done before overwriting slab with h3

    // ---- stage h3 (64 rows x 256 feats = 32KB, rs=512B, XOR), + bias b2
    {
        const float4* B2C = (const float4*)((const char*)ws + (size_t)U_B2C * 16);
        const float4* pb2 = B2C + ((size_t)w * 64 + lane) * 4;
        float4 cv[4];
#pragma unroll
        for (int g = 0; g < 4; ++g) cv[g] = pb2[g];
        int jb = w * 32 + 4 * q;
#pragma unroll
        for (int mt = 0; mt < 2; ++mt) {
            int m = mt * 32 + l31;
#pragma unroll
            for (int t = 0; t < 4; ++t) {
                const float* ct = (const float*)&cv[t];
                f16x4 pk;
#pragma unroll
                for (int r = 0; r < 4; ++r) {
                    float v = acc3[mt][4 * t + r] + ct[r];
                    pk[r] = (f16)(v > 0.f ? v : 0.f);
                }
                slab_write4(lds, m, (jb + 8 * t) >> 1, 512, pk);
            }
        }
    }
    __syncthreads();

    // ---- layer 4: waves 0,1 -> the two 32-row tiles (j padded to 32, 3 valid)
    if (w < 2) {
        f32x16 acc4 = {};
#pragma unroll 4
        for (int ks = 0; ks < 16; ++ks) {
            f16x8 af = W3F[ks * 64 + lane];
            f16x8 bf = slab_read8(lds, w * 32 + l31, (ks * 16 + q * 8) >> 1, 512);
            acc4 = MFMA(af, bf, acc4);
        }
        if (q == 0) {
            size_t gm = rowbase + w * 32 + l31;
            out[gm * 3 + 0] = acc4[0] + b3[0];
            out[gm * 3 + 1] = acc4[1] + b3[1];
            out[gm * 3 + 2] = acc4[2] + b3[2];
        }
    }
}

extern "C" void kernel_launch(void* const* d_in, const int* in_sizes, int n_in,
                              void* d_out, int out_size, void* d_ws, size_t ws_size,
                              hipStream_t stream)
{
    const float* X  = (const float*)d_in[0];
    const float* W0 = (const float*)d_in[1];
    const float* b0 = (const float*)d_in[2];
    const float* W1 = (const float*)d_in[3];
    const float* b1 = (const float*)d_in[4];
    const float* W2 = (const float*)d_in[5];
    const float* b2 = (const float*)d_in[6];
    const float* W3 = (const float*)d_in[7];
    const float* b3 = (const float*)d_in[8];
    f16* ws = (f16*)d_ws;

    int N = in_sizes[0] / 2;          // 262144
    int nblk = N / 64;                // 4096

    prep_kernel<<<(U_TOT2 + 255) / 256, 256, 0, stream>>>(W0, b0, W1, b1, W2, b2, W3, ws);
    mlp_kernel<<<nblk, 512, 0, stream>>>(X, b3, ws, (float*)d_out);
}

// Round 11
// 882.176 us; speedup vs baseline: 2.5171x; 2.5171x over previous
//
#include <hip/hip_runtime.h>

// Fused 4-layer MLP (2 -> 1024 -> 512 -> 256 -> 3), N = 262144, fp32 I/O.
// R11: 1024 thr (16 waves), 128 rows/block, 2048 blocks, 1 block/CU.
// Per-thread shape identical to R8 (acc2[2][2]=64 AGPR, 2jt x 2mt, affine
// rs=520 h1 slab, unroll 2 -> arch demand ~55-60 <= 64): wave w handles
// jt-pair (w&7)*2 and row-half (w>>3). 2x work per block halves per-FLOP
// barrier/stage/tail cost and halves the W1F L2 restream. 131.6 KB dynamic
// LDS -> single-pass affine tail (h2 rs=1028, h3 rs=516; zero XOR VALU).
// Register ledger (R2-R10): 64 AGPR acc + <=64 arch; unroll kept at 2 to cap
// in-flight global frags. NO min-waves pin (R10: pinning forces spill).

typedef _Float16 f16;
typedef f16 f16x8 __attribute__((ext_vector_type(8)));
typedef f16 f16x4 __attribute__((ext_vector_type(4)));
typedef float f32x16 __attribute__((ext_vector_type(16)));

#define MFMA(a, b, c) __builtin_amdgcn_mfma_f32_32x32x16_f16((a), (b), (c), 0, 0, 0)

// h1 slab: 128 rows x 520 B (256 feats*2B + 8B pad; 130 dw -> bank=2m+c,
// 2-way free).  Tail: h2 128 rows x 1028 B (257 dw -> bank=m+c, conflict-
// free); h3 128 rows x 516 B (129 dw -> bank=m+c).
#define RS1 520
#define RS2 1028
#define RS3 516
#define SLABSZ (128 * RS2)   // 131584: max of the three phases

// ws layout in 16-byte units (f16x8):
//  W1F : [16 jt][64 ks][64 lane]            ->      0 .. 65536
//  W2F : [ 8 jt][32 ks][64 lane]            ->  65536 .. 81920
//  W3F : [16 ks][64 lane]                   ->  81920 .. 82944
//  P0F : [32 k1t][64 lane] (layer1 A frag)  ->  82944 .. 84992
//  B1F : [16 jt][64 lane]                   ->  84992 .. 86016
//  B2F : [ 8 jt][64 lane]                   ->  86016 .. 86528
#define U_W1F 0
#define U_W2F 65536
#define U_W3F 81920
#define U_P0F 82944
#define U_B1F 84992
#define U_B2F 86016
#define U_TOTAL 86528

__global__ void prep_kernel(const float* __restrict__ W0, const float* __restrict__ b0,
                            const float* __restrict__ W1, const float* __restrict__ b1,
                            const float* __restrict__ W2, const float* __restrict__ b2,
                            const float* __restrict__ W3, f16* __restrict__ ws)
{
    int u = blockIdx.x * 256 + threadIdx.x;
    if (u >= U_TOTAL) return;
    int lane = u & 63;
    int l31 = lane & 31;
    int q = lane >> 5;
    f16x8 v;
#pragma unroll
    for (int e = 0; e < 8; ++e) v[e] = (f16)0.f;

    if (u < U_W2F) {                       // W1F: W1 is [1024][512]
        int jt = u >> 12, ks = (u >> 6) & 63;
        int j = jt * 32 + l31;
        int kb = ks * 16 + q * 8;
        const float* p = W1 + (size_t)kb * 512 + j;
#pragma unroll
        for (int e = 0; e < 8; ++e) v[e] = (f16)p[(size_t)e * 512];
    } else if (u < U_W3F) {                // W2F: W2 is [512][256]
        int t = u - U_W2F;
        int jt = t >> 11, ks = (t >> 6) & 31;
        int j = jt * 32 + l31;
        int kb = ks * 16 + q * 8;
        const float* p = W2 + (size_t)kb * 256 + j;
#pragma unroll
        for (int e = 0; e < 8; ++e) v[e] = (f16)p[(size_t)e * 256];
    } else if (u < U_P0F) {                // W3F: W3 is [256][3], pad j>=3 with 0
        int t = u - U_W3F;
        int ks = t >> 6;
        int j = l31;
        int kb = ks * 16 + q * 8;
        if (j < 3) {
            const float* p = W3 + (size_t)kb * 3 + j;
#pragma unroll
            for (int e = 0; e < 8; ++e) v[e] = (f16)p[(size_t)e * 3];
        }
    } else if (u < U_B1F) {                // P0F: layer-1 A frag with hi/lo split + bias
        int t = u - U_P0F;
        int jt = t >> 6;
        int j = jt * 32 + l31;
        if (q == 0) {
            float w00 = W0[j], w01 = W0[1024 + j], bb = b0[j];
            f16 w00h = (f16)w00, w01h = (f16)w01, bh = (f16)bb;
            v[0] = w00h; v[1] = w01h; v[2] = bh;
            v[3] = w00h; v[4] = w01h;                       // pair with x_lo
            v[5] = (f16)(w00 - (float)w00h);                // w_lo * x_hi
            v[6] = (f16)(w01 - (float)w01h);
            v[7] = (f16)(bb - (float)bh);                   // bias residual * 1
        }
    } else if (u < U_B2F) {                // B1F
        int t = u - U_B1F;
        int jt = t >> 6;
        int j = jt * 32 + l31;
        if (q == 0) v[0] = (f16)b1[j];
    } else {                               // B2F
        int t = u - U_B2F;
        int jt = t >> 6;
        int j = jt * 32 + l31;
        if (q == 0) v[0] = (f16)b2[j];
    }
    ((f16x8*)ws)[u] = v;
}

__device__ __forceinline__ f16x4 relu_pack4(const f32x16& d, int t)
{
    f16x4 pk;
#pragma unroll
    for (int r = 0; r < 4; ++r) {
        float v = d[4 * t + r];
        pk[r] = (f16)(v > 0.f ? v : 0.f);
    }
    return pk;
}

__device__ __forceinline__ f16x8 aff_read8(const unsigned char* p, int byteoff)
{
    union { f16x8 v; f16x4 h[2]; } u;
    u.h[0] = *(const f16x4*)(p + byteoff);
    u.h[1] = *(const f16x4*)(p + byteoff + 8);
    return u.v;
}

__global__ __launch_bounds__(1024)
void mlp_kernel(const float* __restrict__ X, const float* __restrict__ b3,
                const f16* __restrict__ ws, float* __restrict__ out)
{
    const f16x8* W1F = (const f16x8*)ws + U_W1F;
    const f16x8* W2F = (const f16x8*)ws + U_W2F;
    const f16x8* W3F = (const f16x8*)ws + U_W3F;
    const f16x8* P0F = (const f16x8*)ws + U_P0F;
    const f16x8* B1F = (const f16x8*)ws + U_B1F;
    const f16x8* B2F = (const f16x8*)ws + U_B2F;

    extern __shared__ __align__(16) unsigned char lds[];

    const int tid  = threadIdx.x;
    const int w    = tid >> 6;       // wave 0..15
    const int lane = tid & 63;
    const int l31  = lane & 31;
    const int q    = lane >> 5;
    const int wl   = w & 7;          // jt-pair / k1-slot / L3 jt
    const int mth  = w >> 3;         // row-half 0..1
    const size_t rowbase = (size_t)blockIdx.x * 128;

    // ones frag for bias-init MFMAs (short-lived)
    f16x8 ones;
#pragma unroll
    for (int e = 0; e < 8; ++e) ones[e] = (f16)0.f;
    if (q == 0) ones[0] = (f16)1.f;

    // X frags for this wave's two m-tiles (hi/lo split -> layer 1 ~exact)
    f16x8 xfrag[2];
#pragma unroll
    for (int u = 0; u < 2; ++u) {
        f16x8 v;
#pragma unroll
        for (int e = 0; e < 8; ++e) v[e] = (f16)0.f;
        if (q == 0) {
            float2 xv = ((const float2*)X)[rowbase + (mth * 2 + u) * 32 + l31];
            f16 x0h = (f16)xv.x, x1h = (f16)xv.y;
            v[0] = x0h; v[1] = x1h; v[2] = (f16)1.f;
            v[3] = (f16)(xv.x - (float)x0h);
            v[4] = (f16)(xv.y - (float)x1h);
            v[5] = x0h; v[6] = x1h; v[7] = (f16)1.f;
        }
        xfrag[u] = v;
    }

    // Layer-2 ownership: jt0 = wl*2 (+1); m-tiles 2*mth, 2*mth+1.
    const int jt0 = wl * 2;
    f32x16 acc2[2][2];   // [ji][mt]
#pragma unroll
    for (int ji = 0; ji < 2; ++ji) {
        f32x16 z = {};
        f32x16 binit = MFMA(B1F[(jt0 + ji) * 64 + lane], ones, z);
        acc2[ji][0] = binit;
        acc2[ji][1] = binit;
    }

    // Affine bases (h1 slab, rs=520)
    const unsigned char* pb = lds + (mth * 64 + l31) * RS1 + q * 16;   // bf reads
    unsigned char* pw = lds + (size_t)(mth * 64 + l31) * RS1 + wl * 64 + q * 8;  // stage writes

    // ---- fused layer1 + layer2: 4 chunks x 256 feats
    for (int c = 0; c < 4; ++c) {
        // stage: k1-slot wl, this wave's two m-tiles (2 MFMA + 8 b64 writes)
        {
            f16x8 afp = P0F[(c * 8 + wl) * 64 + lane];
#pragma unroll
            for (int u = 0; u < 2; ++u) {
                f32x16 z = {};
                f32x16 d = MFMA(afp, xfrag[u], z);
#pragma unroll
                for (int t = 0; t < 4; ++t)
                    *(f16x4*)(pw + u * (32 * RS1) + t * 16) = relu_pack4(d, t);
            }
        }
        __syncthreads();
        // K-loop: 16 ks; 2 af (L2), 2 bf (LDS immediate), 4 MFMA
        const f16x8* pa0 = W1F + ((size_t)jt0 * 64 + c * 16) * 64 + lane;
        const f16x8* pa1 = pa0 + 64 * 64;
#pragma unroll 2
        for (int ks = 0; ks < 16; ++ks) {
            f16x8 af0 = pa0[ks * 64];
            f16x8 af1 = pa1[ks * 64];
            f16x8 bf0 = aff_read8(pb, ks * 32);
            f16x8 bf1 = aff_read8(pb, 32 * RS1 + ks * 32);
            acc2[0][0] = MFMA(af0, bf0, acc2[0][0]);
            acc2[0][1] = MFMA(af0, bf1, acc2[0][1]);
            acc2[1][0] = MFMA(af1, bf0, acc2[1][0]);
            acc2[1][1] = MFMA(af1, bf1, acc2[1][1]);
        }
        __syncthreads();
    }

    // ---- stage h2 (128 rows x 512 feats, rs=1028, affine); acc2 dies here
    {
#pragma unroll
        for (int ji = 0; ji < 2; ++ji) {
            unsigned char* ph = lds + (size_t)(jt0 + ji) * 64 + q * 8;
#pragma unroll
            for (int mt = 0; mt < 2; ++mt) {
                unsigned char* phm = ph + (size_t)(mth * 64 + mt * 32 + l31) * RS2;
#pragma unroll
                for (int t = 0; t < 4; ++t)
                    *(f16x4*)(phm + t * 16) = relu_pack4(acc2[ji][mt], t);
            }
        }
    }
    __syncthreads();

    // ---- layer 3 full-K (512): wave w -> j-tile wl, row-half mth
    f32x16 acc3[2];
    {
        f32x16 z = {};
        f32x16 binit = MFMA(B2F[wl * 64 + lane], ones, z);
        acc3[0] = binit;
        acc3[1] = binit;
    }
    {
        const unsigned char* pb3 = lds + (size_t)(mth * 64 + l31) * RS2 + q * 16;
#pragma unroll 2
        for (int ks = 0; ks < 32; ++ks) {
            f16x8 af = W2F[(wl * 32 + ks) * 64 + lane];
            f16x8 bf0 = aff_read8(pb3, ks * 32);
            f16x8 bf1 = aff_read8(pb3, 32 * RS2 + ks * 32);
            acc3[0] = MFMA(af, bf0, acc3[0]);
            acc3[1] = MFMA(af, bf1, acc3[1]);
        }
    }
    __syncthreads();   // h2 reads done before overwriting slab with h3

    // ---- stage h3 (128 rows x 256 feats, rs=516, affine); acc3 dies here
    {
        unsigned char* ph = lds + (size_t)wl * 64 + q * 8;
#pragma unroll
        for (int mt = 0; mt < 2; ++mt) {
            unsigned char* phm = ph + (size_t)(mth * 64 + mt * 32 + l31) * RS3;
#pragma unroll
            for (int t = 0; t < 4; ++t)
                *(f16x4*)(phm + t * 16) = relu_pack4(acc3[mt], t);
        }
    }
    __syncthreads();

    // ---- layer 4: waves 0..3 -> four 32-row tiles (j padded to 32, 3 valid)
    if (w < 4) {
        const unsigned char* pb4 = lds + (size_t)(w * 32 + l31) * RS3 + q * 16;
        f32x16 acc4 = {};
#pragma unroll 2
        for (int ks = 0; ks < 16; ++ks) {
            f16x8 af = W3F[ks * 64 + lane];
            f16x8 bf = aff_read8(pb4, ks * 32);
            acc4 = MFMA(af, bf, acc4);
        }
        if (q == 0) {
            size_t gm = rowbase + w * 32 + l31;
            out[gm * 3 + 0] = acc4[0] + b3[0];
            out[gm * 3 + 1] = acc4[1] + b3[1];
            out[gm * 3 + 2] = acc4[2] + b3[2];
        }
    }
}

extern "C" void kernel_launch(void* const* d_in, const int* in_sizes, int n_in,
                              void* d_out, int out_size, void* d_ws, size_t ws_size,
                              hipStream_t stream)
{
    const float* X  = (const float*)d_in[0];
    const float* W0 = (const float*)d_in[1];
    const float* b0 = (const float*)d_in[2];
    const float* W1 = (const float*)d_in[3];
    const float* b1 = (const float*)d_in[4];
    const float* W2 = (const float*)d_in[5];
    const float* b2 = (const float*)d_in[6];
    const float* W3 = (const float*)d_in[7];
    const float* b3 = (const float*)d_in[8];
    f16* ws = (f16*)d_ws;

    int N = in_sizes[0] / 2;          // 262144
    int nblk = N / 128;               // 2048

    // 131.6 KB dynamic LDS opt-in (idempotent; graph-capture safe)
    (void)hipFuncSetAttribute((const void*)mlp_kernel,
                              hipFuncAttributeMaxDynamicSharedMemorySize, SLABSZ);

    prep_kernel<<<(U_TOTAL + 255) / 256, 256, 0, stream>>>(W0, b0, W1, b1, W2, b2, W3, ws);
    mlp_kernel<<<nblk, 1024, SLABSZ, stream>>>(X, b3, ws, (float*)d_out);
}

// Round 12
// 411.746 us; speedup vs baseline: 5.3930x; 2.1425x over previous
//
#include <hip/hip_runtime.h>

// Fused 4-layer MLP (2 -> 1024 -> 512 -> 256 -> 3), N = 262144, fp32 I/O.
// R12: R8 config exactly (512 thr / 8 waves, 64 rows/block, 4096 blocks,
// 64 KB static LDS, affine rs=520 h1 slab, unroll 4, 2 blocks/CU) + the
// tail's XOR-swizzle addressing made loop-invariant: 8 precomputed base
// registers (lo/hi x ks&3) + immediate offsets for L3/L4 reads. Targets the
// measured 31% VALUBusy (tail address math). Bases live in tail only ->
// main-loop register pressure (the binding 64-arch budget) untouched.
// Ledger of hard-won invariants:
//  - arch VGPR <= 64 with 64 AGPR acc (128/thread -> 4 waves/SIMD);
//    68 arch = 1 blk/CU cliff (R9); pinning min-waves = spill (R10).
//  - TWO independently-phased 8-wave blocks/CU are load-bearing: 16-wave
//    or 1-blk/CU variants phase-lock on barriers and idle (R2-R5, R11).
// fp16 MFMA 32x32x16, fp32 accumulate, transposed layers D[feat][batch].

typedef _Float16 f16;
typedef f16 f16x8 __attribute__((ext_vector_type(8)));
typedef f16 f16x4 __attribute__((ext_vector_type(4)));
typedef float f32x16 __attribute__((ext_vector_type(16)));

#define MFMA(a, b, c) __builtin_amdgcn_mfma_f32_32x32x16_f16((a), (b), (c), 0, 0, 0)

// h1 slab geometry: 64 rows, row stride 520 B (256 feats * 2B + 8B pad)
#define RS1   520
#define MTOFF (32 * RS1)   // 16640: offset of m-tile 1

// ws layout in 16-byte units (f16x8):
//  W1F : [16 jt][64 ks][64 lane]            ->      0 .. 65536
//  W2F : [ 8 jt][32 ks][64 lane]            ->  65536 .. 81920
//  W3F : [16 ks][64 lane]                   ->  81920 .. 82944
//  P0F : [32 k1t][64 lane] (layer1 A frag)  ->  82944 .. 84992
//  B1F : [16 jt][64 lane]                   ->  84992 .. 86016
//  B2F : [ 8 jt][64 lane]                   ->  86016 .. 86528
#define U_W1F 0
#define U_W2F 65536
#define U_W3F 81920
#define U_P0F 82944
#define U_B1F 84992
#define U_B2F 86016
#define U_TOTAL 86528

__global__ void prep_kernel(const float* __restrict__ W0, const float* __restrict__ b0,
                            const float* __restrict__ W1, const float* __restrict__ b1,
                            const float* __restrict__ W2, const float* __restrict__ b2,
                            const float* __restrict__ W3, f16* __restrict__ ws)
{
    int u = blockIdx.x * 256 + threadIdx.x;
    if (u >= U_TOTAL) return;
    int lane = u & 63;
    int l31 = lane & 31;
    int q = lane >> 5;
    f16x8 v;
#pragma unroll
    for (int e = 0; e < 8; ++e) v[e] = (f16)0.f;

    if (u < U_W2F) {                       // W1F: W1 is [1024][512]
        int jt = u >> 12, ks = (u >> 6) & 63;
        int j = jt * 32 + l31;
        int kb = ks * 16 + q * 8;
        const float* p = W1 + (size_t)kb * 512 + j;
#pragma unroll
        for (int e = 0; e < 8; ++e) v[e] = (f16)p[(size_t)e * 512];
    } else if (u < U_W3F) {                // W2F: W2 is [512][256]
        int t = u - U_W2F;
        int jt = t >> 11, ks = (t >> 6) & 31;
        int j = jt * 32 + l31;
        int kb = ks * 16 + q * 8;
        const float* p = W2 + (size_t)kb * 256 + j;
#pragma unroll
        for (int e = 0; e < 8; ++e) v[e] = (f16)p[(size_t)e * 256];
    } else if (u < U_P0F) {                // W3F: W3 is [256][3], pad j>=3 with 0
        int t = u - U_W3F;
        int ks = t >> 6;
        int j = l31;
        int kb = ks * 16 + q * 8;
        if (j < 3) {
            const float* p = W3 + (size_t)kb * 3 + j;
#pragma unroll
            for (int e = 0; e < 8; ++e) v[e] = (f16)p[(size_t)e * 3];
        }
    } else if (u < U_B1F) {                // P0F: layer-1 A frag with hi/lo split + bias
        int t = u - U_P0F;
        int jt = t >> 6;
        int j = jt * 32 + l31;
        if (q == 0) {
            float w00 = W0[j], w01 = W0[1024 + j], bb = b0[j];
            f16 w00h = (f16)w00, w01h = (f16)w01, bh = (f16)bb;
            v[0] = w00h; v[1] = w01h; v[2] = bh;
            v[3] = w00h; v[4] = w01h;                       // pair with x_lo
            v[5] = (f16)(w00 - (float)w00h);                // w_lo * x_hi
            v[6] = (f16)(w01 - (float)w01h);
            v[7] = (f16)(bb - (float)bh);                   // bias residual * 1
        }
    } else if (u < U_B2F) {                // B1F
        int t = u - U_B1F;
        int jt = t >> 6;
        int j = jt * 32 + l31;
        if (q == 0) v[0] = (f16)b1[j];
    } else {                               // B2F
        int t = u - U_B2F;
        int jt = t >> 6;
        int j = jt * 32 + l31;
        if (q == 0) v[0] = (f16)b2[j];
    }
    ((f16x8*)ws)[u] = v;
}

// ---- XOR-swizzled slab write helper (tail h2/h3 staging; once per block).
__device__ __forceinline__ void slab_write4(unsigned char* lds, int m, int dw /*even*/,
                                            int rs, f16x4 val)
{
    int s = (m & 15) << 1;
    *(f16x4*)(lds + (size_t)m * rs + (size_t)((dw ^ s) << 2)) = val;
}

__device__ __forceinline__ f16x4 relu_pack4(const f32x16& d, int t)
{
    f16x4 pk;
#pragma unroll
    for (int r = 0; r < 4; ++r) {
        float v = d[4 * t + r];
        pk[r] = (f16)(v > 0.f ? v : 0.f);
    }
    return pk;
}

__global__ __launch_bounds__(512)
void mlp_kernel(const float* __restrict__ X, const float* __restrict__ b3,
                const f16* __restrict__ ws, float* __restrict__ out)
{
    const f16x8* W1F = (const f16x8*)ws + U_W1F;
    const f16x8* W2F = (const f16x8*)ws + U_W2F;
    const f16x8* W3F = (const f16x8*)ws + U_W3F;
    const f16x8* P0F = (const f16x8*)ws + U_P0F;
    const f16x8* B1F = (const f16x8*)ws + U_B1F;
    const f16x8* B2F = (const f16x8*)ws + U_B2F;

    __shared__ __align__(16) unsigned char lds[65536];

    const int tid  = threadIdx.x;
    const int w    = tid >> 6;       // wave 0..7
    const int lane = tid & 63;
    const int l31  = lane & 31;
    const int q    = lane >> 5;
    const size_t rowbase = (size_t)blockIdx.x * 64;

    f32x16 zero16;
#pragma unroll
    for (int i = 0; i < 16; ++i) zero16[i] = 0.f;

    // ones frag for bias-init MFMAs
    f16x8 ones;
#pragma unroll
    for (int e = 0; e < 8; ++e) ones[e] = (f16)0.f;
    if (q == 0) ones[0] = (f16)1.f;

    // X frags for both m-tiles (hi/lo split -> layer 1 ~exact)
    f16x8 xfrag[2];
#pragma unroll
    for (int mt = 0; mt < 2; ++mt) {
        f16x8 v;
#pragma unroll
        for (int e = 0; e < 8; ++e) v[e] = (f16)0.f;
        if (q == 0) {
            float2 xv = ((const float2*)X)[rowbase + mt * 32 + l31];
            f16 x0h = (f16)xv.x, x1h = (f16)xv.y;
            v[0] = x0h; v[1] = x1h; v[2] = (f16)1.f;
            v[3] = (f16)(xv.x - (float)x0h);
            v[4] = (f16)(xv.y - (float)x1h);
            v[5] = x0h; v[6] = x1h; v[7] = (f16)1.f;
        }
        xfrag[mt] = v;
    }

    // Layer-2 ownership: wave w -> j-tiles 2w, 2w+1; both m-tiles.
    const int jt0 = w * 2;
    f32x16 acc2[2][2];   // [ji][mt]
#pragma unroll
    for (int ji = 0; ji < 2; ++ji) {
        f32x16 binit = MFMA(B1F[(jt0 + ji) * 64 + lane], ones, zero16);
        acc2[ji][0] = binit;
        acc2[ji][1] = binit;
    }

    // Affine h1-slab base for this thread's bf reads: row l31, feat-byte q*16.
    const unsigned char* pb = lds + l31 * RS1 + q * 16;

    // ---- fused layer1 + layer2: K chunked 4 x 256 through affine slab
    for (int c = 0; c < 4; ++c) {
        // layer 1: wave w -> k1-tile w (chunk-local), both m-tiles.
        {
            f16x8 af1 = P0F[(c * 8 + w) * 64 + lane];
            unsigned char* pw = lds + w * 64 + q * 8;
#pragma unroll
            for (int mt = 0; mt < 2; ++mt) {
                f32x16 d = MFMA(af1, xfrag[mt], zero16);
                unsigned char* pwm = pw + (mt * 32 + l31) * RS1;
#pragma unroll
                for (int t = 0; t < 4; ++t)
                    *(f16x4*)(pwm + t * 16) = relu_pack4(d, t);
            }
        }
        __syncthreads();
        // layer 2 partial K: 16 ks; 2 af (L2, imm13+bump), 2 bf (LDS, pure
        // immediate offsets), 4 MFMA.
        const f16x8* pa0 = W1F + ((size_t)jt0 * 64 + c * 16) * 64 + lane;
        const f16x8* pa1 = pa0 + 64 * 64;
#pragma unroll 4
        for (int ks = 0; ks < 16; ++ks) {
            f16x8 af0 = pa0[ks * 64];
            f16x8 af1 = pa1[ks * 64];
            union { f16x8 v; f16x4 p[2]; } u0, u1;
            u0.p[0] = *(const f16x4*)(pb + ks * 32);
            u0.p[1] = *(const f16x4*)(pb + ks * 32 + 8);
            u1.p[0] = *(const f16x4*)(pb + MTOFF + ks * 32);
            u1.p[1] = *(const f16x4*)(pb + MTOFF + ks * 32 + 8);
            acc2[0][0] = MFMA(af0, u0.v, acc2[0][0]);
            acc2[0][1] = MFMA(af0, u1.v, acc2[0][1]);
            acc2[1][0] = MFMA(af1, u0.v, acc2[1][0]);
            acc2[1][1] = MFMA(af1, u1.v, acc2[1][1]);
        }
        __syncthreads();
    }

    // ---- stage h2 (64 rows x 512 feats = 64KB, rs=1024B, XOR); acc2 dies here
#pragma unroll
    for (int ji = 0; ji < 2; ++ji) {
        int jb = (jt0 + ji) * 32 + 4 * q;
#pragma unroll
        for (int mt = 0; mt < 2; ++mt) {
            int m = mt * 32 + l31;
#pragma unroll
            for (int t = 0; t < 4; ++t)
                slab_write4(lds, m, (jb + 8 * t) >> 1, 1024,
                            relu_pack4(acc2[ji][mt], t));
        }
    }
    __syncthreads();

    // Precomputed XOR-swizzle bases (TAIL-ONLY registers; computed after the
    // main loop so the binding 64-arch main-loop budget is untouched).
    // byteoff(m, ks) = m*rs + ((dw ^ s) << 2), dw = ks*8 + q*4, s = (m&15)<<1.
    // ks>>2 lives above the XOR'd bits: offset = base[ks&3] + (ks>>2)*128.
    const int s_ = (l31 & 15) << 1;
    unsigned bl[4], bh[4];
#pragma unroll
    for (int j = 0; j < 4; ++j) {
        int dwj = j * 8 + q * 4;
        bl[j] = (unsigned)(((dwj)     ^ s_) << 2);
        bh[j] = (unsigned)(((dwj + 2) ^ s_) << 2);
    }

    // ---- layer 3 full-K (512): wave w -> j-tile w, both m-tiles
    f32x16 acc3[2];
    {
        f32x16 binit = MFMA(B2F[w * 64 + lane], ones, zero16);
        acc3[0] = binit;
        acc3[1] = binit;
    }
    {
        const f16x8* pa3 = W2F + (size_t)(w * 32) * 64 + lane;
        const unsigned m0 = (unsigned)l31 * 1024;
        const unsigned m1 = m0 + 32 * 1024;
#pragma unroll 4
        for (int ks = 0; ks < 32; ++ks) {
            f16x8 af = pa3[ks * 64];
            const int j = ks & 3;
            const int a = (ks >> 2) * 128;
            union { f16x8 v; f16x4 p[2]; } u0, u1;
            u0.p[0] = *(const f16x4*)(lds + m0 + bl[j] + a);
            u0.p[1] = *(const f16x4*)(lds + m0 + bh[j] + a);
            u1.p[0] = *(const f16x4*)(lds + m1 + bl[j] + a);
            u1.p[1] = *(const f16x4*)(lds + m1 + bh[j] + a);
            acc3[0] = MFMA(af, u0.v, acc3[0]);
            acc3[1] = MFMA(af, u1.v, acc3[1]);
        }
    }
    __syncthreads();   // h2 reads done before overwriting slab with h3

    // ---- stage h3 (64 rows x 256 feats = 32KB, rs=512B, XOR); acc3 dies here
    {
        int jb = w * 32 + 4 * q;
#pragma unroll
        for (int mt = 0; mt < 2; ++mt) {
            int m = mt * 32 + l31;
#pragma unroll
            for (int t = 0; t < 4; ++t)
                slab_write4(lds, m, (jb + 8 * t) >> 1, 512,
                            relu_pack4(acc3[mt], t));
        }
    }
    __syncthreads();

    // ---- layer 4: waves 0,1 -> the two 32-row tiles (j padded to 32, 3 valid)
    if (w < 2) {
        const f16x8* pa4 = W3F + lane;
        const unsigned m4 = (unsigned)(w * 32 + l31) * 512;
        f32x16 acc4 = zero16;
#pragma unroll 4
        for (int ks = 0; ks < 16; ++ks) {
            f16x8 af = pa4[ks * 64];
            const int j = ks & 3;
            const int a = (ks >> 2) * 128;
            union { f16x8 v; f16x4 p[2]; } u0;
            u0.p[0] = *(const f16x4*)(lds + m4 + bl[j] + a);
            u0.p[1] = *(const f16x4*)(lds + m4 + bh[j] + a);
            acc4 = MFMA(af, u0.v, acc4);
        }
        if (q == 0) {
            size_t gm = rowbase + w * 32 + l31;
            out[gm * 3 + 0] = acc4[0] + b3[0];
            out[gm * 3 + 1] = acc4[1] + b3[1];
            out[gm * 3 + 2] = acc4[2] + b3[2];
        }
    }
}

extern "C" void kernel_launch(void* const* d_in, const int* in_sizes, int n_in,
                              void* d_out, int out_size, void* d_ws, size_t ws_size,
                              hipStream_t stream)
{
    const float* X  = (const float*)d_in[0];
    const float* W0 = (const float*)d_in[1];
    const float* b0 = (const float*)d_in[2];
    const float* W1 = (const float*)d_in[3];
    const float* b1 = (const float*)d_in[4];
    const float* W2 = (const float*)d_in[5];
    const float* b2 = (const float*)d_in[6];
    const float* W3 = (const float*)d_in[7];
    const float* b3 = (const float*)d_in[8];
    f16* ws = (f16*)d_ws;

    int N = in_sizes[0] / 2;          // 262144
    int nblk = N / 64;                // 4096

    prep_kernel<<<(U_TOTAL + 255) / 256, 256, 0, stream>>>(W0, b0, W1, b1, W2, b2, W3, ws);
    mlp_kernel<<<nblk, 512, 0, stream>>>(X, b3, ws, (float*)d_out);
}